// Round 1
// baseline (11399.154 us; speedup 1.0000x reference)
//
#include <hip/hip_runtime.h>
#include <math.h>

#define NEGINF (-INFINITY)
#define NBOX 5625

// ---------------- conv 3x3 512->512 + bias + relu, output transposed [p][c] ----------------
// grid (64 oc-groups, 5 row-groups), block 128 (125 active)
__global__ __launch_bounds__(128) void conv3x3_relu(
    const float* __restrict__ feat, const float* __restrict__ w,
    const float* __restrict__ bias, float* __restrict__ xt) {
  const int ocg = blockIdx.x;      // 0..63 -> oc = ocg*8 .. +7
  const int pg  = blockIdx.y;      // 0..4  -> rows pg*5 .. pg*5+4
  const int t = threadIdx.x;
  const int lr = t / 25, lc = t % 25;
  const bool active = t < 125;
  const int h = pg * 5 + lr;
  __shared__ float sp[7][25];      // rows pg*5-1 .. pg*5+5
  float acc[8];
#pragma unroll
  for (int o = 0; o < 8; o++) acc[o] = 0.f;
  const int r0 = pg * 5 - 1;
  for (int ic = 0; ic < 512; ++ic) {
    __syncthreads();
    for (int idx = t; idx < 175; idx += 128) {
      int rr = idx / 25, cc = idx % 25;
      int gr = r0 + rr;
      sp[rr][cc] = (gr >= 0 && gr < 25) ? feat[ic * 625 + gr * 25 + cc] : 0.f;
    }
    __syncthreads();
    if (active) {
      float v[9];
#pragma unroll
      for (int dy = 0; dy < 3; dy++) {
        v[dy * 3 + 0] = (lc > 0)  ? sp[lr + dy][lc - 1] : 0.f;
        v[dy * 3 + 1] = sp[lr + dy][lc];
        v[dy * 3 + 2] = (lc < 24) ? sp[lr + dy][lc + 1] : 0.f;
      }
      const float* wp = w + ((size_t)(ocg * 8) * 512 + ic) * 9;
#pragma unroll
      for (int o = 0; o < 8; o++) {
        const float* wo = wp + (size_t)o * 512 * 9;
        float s = acc[o];
#pragma unroll
        for (int k = 0; k < 9; k++) s = fmaf(v[k], wo[k], s);
        acc[o] = s;
      }
    }
  }
  if (active) {
    int p = h * 25 + lc;
#pragma unroll
    for (int o = 0; o < 8; o++) {
      int oc = ocg * 8 + o;
      xt[(size_t)p * 512 + oc] = fmaxf(acc[o] + bias[oc], 0.f);
    }
  }
}

// ---------------- 1x1 convs: cls (18) + reg (36), output [p][54] ----------------
__global__ void conv1x1_kernel(const float* __restrict__ xt,
    const float* __restrict__ cls_w, const float* __restrict__ cls_b,
    const float* __restrict__ reg_w, const float* __restrict__ reg_b,
    float* __restrict__ out) {
  int gid = blockIdx.x * blockDim.x + threadIdx.x;
  int p = gid >> 6, c = gid & 63;
  if (p >= 625 || c >= 54) return;
  const float* wrow;
  float b;
  if (c < 18) { wrow = cls_w + (size_t)c * 512; b = cls_b[c]; }
  else        { wrow = reg_w + (size_t)(c - 18) * 512; b = reg_b[c - 18]; }
  const float* xr = xt + (size_t)p * 512;
  float s = 0.f;
  for (int k = 0; k < 512; k++) s = fmaf(xr[k], wrow[k], s);
  out[p * 54 + c] = s + b;
}

// ---------------- softmax + anchors + decode + clip + min-size filter ----------------
__global__ void decode_kernel(const float* __restrict__ clsreg,
    const int* __restrict__ Hp, const int* __restrict__ Wp,
    float* __restrict__ boxes, float* __restrict__ areas, float* __restrict__ scores) {
  int n = blockIdx.x * blockDim.x + threadIdx.x;
  if (n >= NBOX) return;
  int p = n / 9, a = n % 9;
  int hh = p / 25, ww = p % 25;
  float Wlim = (float)(*Wp), Hlim = (float)(*Hp);
  float stride = (float)((*Wp) / 25);
  // base anchor: a = ratio_idx*3 + size_idx
  int ri = a / 3, si = a % 3;
  float ratio = (ri == 0) ? 0.5f : ((ri == 1) ? 1.0f : 2.0f);
  float size  = (si == 0) ? 128.f : ((si == 1) ? 256.f : 512.f);
  float hr = sqrtf(ratio);
  float wr = 1.0f / hr;
  float wsz = wr * size, hsz = hr * size;
  // jnp.round = round half to even = rintf
  float bx1 = rintf(-wsz * 0.5f), by1 = rintf(-hsz * 0.5f);
  float bx2 = rintf( wsz * 0.5f), by2 = rintf( hsz * 0.5f);
  float sx = (float)ww * stride, sy = (float)hh * stride;
  float a0 = sx + bx1, a1 = sy + by1, a2 = sx + bx2, a3 = sy + by2;
  float ax = (a0 + a2) * 0.5f, ay = (a1 + a3) * 0.5f;
  float aw = fmaxf(a2 - a0, 1e-6f), ah = fmaxf(a3 - a1, 1e-6f);
  const float* row = clsreg + p * 54;
  // softmax over 2 classes, take class 1 (matches jax.nn.softmax numerics)
  float c0 = row[a * 2], c1 = row[a * 2 + 1];
  float m = fmaxf(c0, c1);
  float e0 = expf(c0 - m), e1 = expf(c1 - m);
  float prob = e1 / (e0 + e1);
  float tx = row[18 + a * 4 + 0], ty = row[18 + a * 4 + 1];
  float tw = row[18 + a * 4 + 2], th = row[18 + a * 4 + 3];
  float px = tx * aw + ax, py = ty * ah + ay;
  float pw = aw * fminf(expf(tw), 1e6f);
  float ph = ah * fminf(expf(th), 1e6f);
  float x1 = px - 0.5f * pw, y1 = py - 0.5f * ph;
  float x2 = px + 0.5f * pw, y2 = py + 0.5f * ph;
  x1 = fminf(fmaxf(x1, 0.f), Wlim - 1.f); x2 = fminf(fmaxf(x2, 0.f), Wlim - 1.f);
  y1 = fminf(fmaxf(y1, 0.f), Hlim - 1.f); y2 = fminf(fmaxf(y2, 0.f), Hlim - 1.f);
  float bw = fmaxf(x2 - x1, 0.f), bh = fmaxf(y2 - y1, 0.f);
  bool ok = (bw >= 1.0f) && (bh >= 1.0f);
  boxes[n * 4 + 0] = x1; boxes[n * 4 + 1] = y1;
  boxes[n * 4 + 2] = x2; boxes[n * 4 + 3] = y2;
  areas[n] = (x2 - x1) * (y2 - y1);
  scores[n] = ok ? prob : NEGINF;
}

// ---------------- greedy NMS, single block. Writes proposals + valid to d_out ----------------
// argmax with tie-break lowest-index == stable top_k sort + argmax in reference.
__global__ __launch_bounds__(1024) void nms_kernel(
    const float* __restrict__ boxes, const float* __restrict__ areas,
    const float* __restrict__ scores_g, float* __restrict__ dout) {
  float* props  = dout;          // [1000][4]
  float* validf = dout + 4000;   // [1000]
  const int t = threadIdx.x;
  float bx1[6], by1[6], bx2[6], by2[6], bar[6], bs[6];
  int bn[6];
#pragma unroll
  for (int k = 0; k < 6; k++) {
    int n = t + k * 1024;
    bn[k] = n;
    if (n < NBOX) {
      bx1[k] = boxes[n * 4 + 0]; by1[k] = boxes[n * 4 + 1];
      bx2[k] = boxes[n * 4 + 2]; by2[k] = boxes[n * 4 + 3];
      bar[k] = areas[n]; bs[k] = scores_g[n];
    } else {
      bx1[k] = by1[k] = bx2[k] = by2[k] = 0.f; bar[k] = 0.f; bs[k] = NEGINF;
    }
  }
  __shared__ float rs[16];
  __shared__ int rn[16];
  __shared__ float bb[5];
  __shared__ int sel;
  const int lane = t & 63, wid = t >> 6;
  for (int i = 0; i < 1000; i++) {
    float ms = NEGINF; int mn = 0x7fffffff;
#pragma unroll
    for (int k = 0; k < 6; k++)
      if (bs[k] > ms || (bs[k] == ms && bn[k] < mn)) { ms = bs[k]; mn = bn[k]; }
#pragma unroll
    for (int off = 32; off >= 1; off >>= 1) {
      float os = __shfl_xor(ms, off);
      int   on = __shfl_xor(mn, off);
      if (os > ms || (os == ms && on < mn)) { ms = os; mn = on; }
    }
    if (lane == 0) { rs[wid] = ms; rn[wid] = mn; }
    __syncthreads();
    if (t == 0) {
      float S = NEGINF; int J = 0x7fffffff;
      for (int wdx = 0; wdx < 16; wdx++)
        if (rs[wdx] > S || (rs[wdx] == S && rn[wdx] < J)) { S = rs[wdx]; J = rn[wdx]; }
      sel = (S > NEGINF) ? J : -1;
    }
    __syncthreads();
    int j = sel;
    if (j < 0) {
      // all remaining iterations are invalid: zero-fill and exit
      for (int z = i * 4 + t; z < 4000; z += 1024) props[z] = 0.f;
      for (int z = i + t; z < 1000; z += 1024) validf[z] = 0.f;
      return;
    }
    if (t == (j & 1023)) {
      int k = j >> 10;
      bb[0] = bx1[k]; bb[1] = by1[k]; bb[2] = bx2[k]; bb[3] = by2[k]; bb[4] = bar[k];
      bs[k] = NEGINF;
    }
    __syncthreads();
    float jx1 = bb[0], jy1 = bb[1], jx2 = bb[2], jy2 = bb[3], jar = bb[4];
#pragma unroll
    for (int k = 0; k < 6; k++) {
      float iw = fmaxf(fminf(bx2[k], jx2) - fmaxf(bx1[k], jx1), 0.f);
      float ih = fmaxf(fminf(by2[k], jy2) - fmaxf(by1[k], jy1), 0.f);
      float inter = iw * ih;
      float iou = inter / fmaxf(bar[k] + jar - inter, 1e-12f);
      if (iou > 0.7f) bs[k] = NEGINF;
    }
    if (t == 0) {
      props[i * 4 + 0] = jx1; props[i * 4 + 1] = jy1;
      props[i * 4 + 2] = jx2; props[i * 4 + 3] = jy2;
      validf[i] = 1.0f;
    }
  }
}

// ---------------- ROI max-pool: feats[r][c*49 + i*7 + j] ----------------
__global__ __launch_bounds__(256) void roipool_kernel(
    const float* __restrict__ feat, const float* __restrict__ dout,
    const int* __restrict__ Wp, float* __restrict__ feats) {
  const int r = blockIdx.x;
  const int t = threadIdx.x;
  const float* props  = dout;
  const float* validf = dout + 4000;
  float* outr = feats + (size_t)r * 25088;
  if (validf[r] == 0.0f) {
    for (int i = t; i < 25088; i += 256) outr[i] = 0.f;
    return;
  }
  const float scale = 1.0f / (float)((*Wp) / 25);
  __shared__ int hs_[7], he_[7], ws_[7], we_[7];
  if (t < 7) {
    float fx1 = props[r * 4 + 0], fy1 = props[r * 4 + 1];
    float fx2 = props[r * 4 + 2], fy2 = props[r * 4 + 3];
    int x1 = (int)rintf(fx1 * scale), y1 = (int)rintf(fy1 * scale);
    int x2 = (int)rintf(fx2 * scale), y2 = (int)rintf(fy2 * scale);
    float roiw = (float)max(x2 - x1 + 1, 1);
    float roih = (float)max(y2 - y1 + 1, 1);
    float bw = roiw / 7.0f, bh = roih / 7.0f;
    float jf = (float)t;
    int w0 = (int)floorf(jf * bw) + x1;
    int w1 = (int)ceilf((jf + 1.f) * bw) + x1;
    int h0 = (int)floorf(jf * bh) + y1;
    int h1 = (int)ceilf((jf + 1.f) * bh) + y1;
    ws_[t] = min(max(w0, 0), 25); we_[t] = min(max(w1, 0), 25);
    hs_[t] = min(max(h0, 0), 25); he_[t] = min(max(h1, 0), 25);
  }
  __syncthreads();
  for (int idx = t; idx < 25088; idx += 256) {
    int c = idx / 49;
    int ij = idx % 49;
    int i = ij / 7, j = ij % 7;
    int h0 = hs_[i], h1 = min(he_[i], h0 + 6);   // ROI_PAD = 6
    int w0 = ws_[j], w1 = min(we_[j], w0 + 6);
    float m = NEGINF;
    const float* fp = feat + (size_t)c * 625;
    for (int y = h0; y < h1; y++)
      for (int x = w0; x < w1; x++)
        m = fmaxf(m, fp[y * 25 + x]);
    outr[idx] = (h0 < h1 && w0 < w1) ? m : 0.0f;  // empty bin -> 0
  }
}

// ---------------- f32 GEMM: C[M,N] = A[M,K] * B[N,K]^T + bias ----------------
// BM=BN=128, BK=16, block 256, 8x8 micro-tile. K must be multiple of 16.
__global__ __launch_bounds__(256) void gemm_f32(
    const float* __restrict__ A, const float* __restrict__ B,
    const float* __restrict__ bias, float* __restrict__ C,
    int M, int N, int K) {
  __shared__ float As[16][128];
  __shared__ float Bs[16][128];
  const int t = threadIdx.x;
  const int tx = t & 15, ty = t >> 4;
  const int m0 = blockIdx.x * 128, n0 = blockIdx.y * 128;
  float acc[8][8];
#pragma unroll
  for (int i = 0; i < 8; i++)
#pragma unroll
    for (int j = 0; j < 8; j++) acc[i][j] = 0.f;
  for (int kt = 0; kt < K; kt += 16) {
#pragma unroll
    for (int l = 0; l < 2; l++) {
      int e = t + l * 256;
      int mm = e >> 2;
      int kk = (e & 3) << 2;
      int gm = m0 + mm;
      float4 va = make_float4(0.f, 0.f, 0.f, 0.f);
      if (gm < M) va = *(const float4*)(A + (size_t)gm * K + kt + kk);
      As[kk + 0][mm] = va.x; As[kk + 1][mm] = va.y;
      As[kk + 2][mm] = va.z; As[kk + 3][mm] = va.w;
      int gn = n0 + mm;
      float4 vb = make_float4(0.f, 0.f, 0.f, 0.f);
      if (gn < N) vb = *(const float4*)(B + (size_t)gn * K + kt + kk);
      Bs[kk + 0][mm] = vb.x; Bs[kk + 1][mm] = vb.y;
      Bs[kk + 2][mm] = vb.z; Bs[kk + 3][mm] = vb.w;
    }
    __syncthreads();
#pragma unroll
    for (int kk = 0; kk < 16; kk++) {
      float a[8], b[8];
      *(float4*)&a[0] = *(const float4*)&As[kk][ty * 8];
      *(float4*)&a[4] = *(const float4*)&As[kk][ty * 8 + 4];
      *(float4*)&b[0] = *(const float4*)&Bs[kk][tx * 8];
      *(float4*)&b[4] = *(const float4*)&Bs[kk][tx * 8 + 4];
#pragma unroll
      for (int i = 0; i < 8; i++)
#pragma unroll
        for (int j = 0; j < 8; j++)
          acc[i][j] = fmaf(a[i], b[j], acc[i][j]);
    }
    __syncthreads();
  }
#pragma unroll
  for (int i = 0; i < 8; i++) {
    int gm = m0 + ty * 8 + i;
    if (gm >= M) continue;
#pragma unroll
    for (int j = 0; j < 8; j++) {
      int gn = n0 + tx * 8 + j;
      if (gn < N) C[(size_t)gm * N + gn] = acc[i][j] + bias[gn];
    }
  }
}

extern "C" void kernel_launch(void* const* d_in, const int* in_sizes, int n_in,
                              void* d_out, int out_size, void* d_ws, size_t ws_size,
                              hipStream_t stream) {
  const float* features    = (const float*)d_in[0];
  const float* conv_w      = (const float*)d_in[1];
  const float* conv_b      = (const float*)d_in[2];
  const float* cls_w       = (const float*)d_in[3];
  const float* cls_b       = (const float*)d_in[4];
  const float* reg_w       = (const float*)d_in[5];
  const float* reg_b       = (const float*)d_in[6];
  const float* fc1_w       = (const float*)d_in[7];
  const float* fc1_b       = (const float*)d_in[8];
  const float* fc2_w       = (const float*)d_in[9];
  const float* fc2_b       = (const float*)d_in[10];
  const float* cls_score_w = (const float*)d_in[11];
  const float* cls_score_b = (const float*)d_in[12];
  const float* bbox_w      = (const float*)d_in[13];
  const float* bbox_b      = (const float*)d_in[14];
  const int*   Hp          = (const int*)d_in[15];
  const int*   Wp          = (const int*)d_in[16];
  float* out = (float*)d_out;

  // workspace layout (floats)
  float* ws     = (float*)d_ws;
  float* xt     = ws;                    // 625*512      = 320000
  float* clsreg = xt + 320000;           // 625*54       = 33750
  float* boxes  = clsreg + 33750;        // 5625*4       = 22500
  float* areas  = boxes + 22500;         // 5625
  float* scores = areas + 5625;          // 5625
  float* feats  = scores + 5625;         // 1000*25088   = 25088000
  float* h1     = feats + 25088000;      // 1000*4096    = 4096000
  float* h2     = h1 + 4096000;          // 1000*4096    = 4096000
  // total = 33,667,500 floats = 134.7 MB

  conv3x3_relu<<<dim3(64, 5), 128, 0, stream>>>(features, conv_w, conv_b, xt);
  conv1x1_kernel<<<dim3(157), 256, 0, stream>>>(xt, cls_w, cls_b, reg_w, reg_b, clsreg);
  decode_kernel<<<dim3(23), 256, 0, stream>>>(clsreg, Hp, Wp, boxes, areas, scores);
  nms_kernel<<<dim3(1), 1024, 0, stream>>>(boxes, areas, scores, out);
  roipool_kernel<<<dim3(1000), 256, 0, stream>>>(features, out, Wp, feats);
  // fc1: (1000,25088) x (4096,25088)^T
  gemm_f32<<<dim3(8, 32), 256, 0, stream>>>(feats, fc1_w, fc1_b, h1, 1000, 4096, 25088);
  // fc2: (1000,4096) x (4096,4096)^T
  gemm_f32<<<dim3(8, 32), 256, 0, stream>>>(h1, fc2_w, fc2_b, h2, 1000, 4096, 4096);
  // logits: (1000,21)
  gemm_f32<<<dim3(8, 1), 256, 0, stream>>>(h2, cls_score_w, cls_score_b, out + 5000, 1000, 21, 4096);
  // deltas: (1000,4)
  gemm_f32<<<dim3(8, 1), 256, 0, stream>>>(h2, bbox_w, bbox_b, out + 26000, 1000, 4, 4096);
}

// Round 2
// 6213.319 us; speedup vs baseline: 1.8346x; 1.8346x over previous
//
#include <hip/hip_runtime.h>
#include <math.h>

#define NEGINF (-INFINITY)
#define NBOX 5625

typedef __attribute__((ext_vector_type(8))) short short8;
typedef __attribute__((ext_vector_type(4))) float floatx4;

__device__ __forceinline__ unsigned short f2bf(float f) {
  unsigned u = __float_as_uint(f);
  u += 0x7fffu + ((u >> 16) & 1u);   // round-to-nearest-even
  return (unsigned short)(u >> 16);
}

__device__ __forceinline__ void gload16(const void* g, void* l) {
  __builtin_amdgcn_global_load_lds(
      (const __attribute__((address_space(1))) void*)g,
      (__attribute__((address_space(3))) void*)l, 16, 0, 0);
}

// ---------------- conv 3x3 512->512 + bias + relu, output transposed [p][c] ----------------
__global__ __launch_bounds__(128) void conv3x3_relu(
    const float* __restrict__ feat, const float* __restrict__ w,
    const float* __restrict__ bias, float* __restrict__ xt) {
  const int ocg = blockIdx.x;      // 0..63 -> oc = ocg*8 .. +7
  const int pg  = blockIdx.y;      // 0..4  -> rows pg*5 .. pg*5+4
  const int t = threadIdx.x;
  const int lr = t / 25, lc = t % 25;
  const bool active = t < 125;
  const int h = pg * 5 + lr;
  __shared__ float sp[7][25];
  float acc[8];
#pragma unroll
  for (int o = 0; o < 8; o++) acc[o] = 0.f;
  const int r0 = pg * 5 - 1;
  for (int ic = 0; ic < 512; ++ic) {
    __syncthreads();
    for (int idx = t; idx < 175; idx += 128) {
      int rr = idx / 25, cc = idx % 25;
      int gr = r0 + rr;
      sp[rr][cc] = (gr >= 0 && gr < 25) ? feat[ic * 625 + gr * 25 + cc] : 0.f;
    }
    __syncthreads();
    if (active) {
      float v[9];
#pragma unroll
      for (int dy = 0; dy < 3; dy++) {
        v[dy * 3 + 0] = (lc > 0)  ? sp[lr + dy][lc - 1] : 0.f;
        v[dy * 3 + 1] = sp[lr + dy][lc];
        v[dy * 3 + 2] = (lc < 24) ? sp[lr + dy][lc + 1] : 0.f;
      }
      const float* wp = w + ((size_t)(ocg * 8) * 512 + ic) * 9;
#pragma unroll
      for (int o = 0; o < 8; o++) {
        const float* wo = wp + (size_t)o * 512 * 9;
        float s = acc[o];
#pragma unroll
        for (int k = 0; k < 9; k++) s = fmaf(v[k], wo[k], s);
        acc[o] = s;
      }
    }
  }
  if (active) {
    int p = h * 25 + lc;
#pragma unroll
    for (int o = 0; o < 8; o++) {
      int oc = ocg * 8 + o;
      xt[(size_t)p * 512 + oc] = fmaxf(acc[o] + bias[oc], 0.f);
    }
  }
}

// ---------------- 1x1 convs: cls (18) + reg (36), output [p][54] ----------------
__global__ void conv1x1_kernel(const float* __restrict__ xt,
    const float* __restrict__ cls_w, const float* __restrict__ cls_b,
    const float* __restrict__ reg_w, const float* __restrict__ reg_b,
    float* __restrict__ out) {
  int gid = blockIdx.x * blockDim.x + threadIdx.x;
  int p = gid >> 6, c = gid & 63;
  if (p >= 625 || c >= 54) return;
  const float* wrow;
  float b;
  if (c < 18) { wrow = cls_w + (size_t)c * 512; b = cls_b[c]; }
  else        { wrow = reg_w + (size_t)(c - 18) * 512; b = reg_b[c - 18]; }
  const float* xr = xt + (size_t)p * 512;
  float s = 0.f;
  for (int k = 0; k < 512; k++) s = fmaf(xr[k], wrow[k], s);
  out[p * 54 + c] = s + b;
}

// ---------------- softmax + anchors + decode + clip + min-size filter ----------------
__global__ void decode_kernel(const float* __restrict__ clsreg,
    const int* __restrict__ Hp, const int* __restrict__ Wp,
    float* __restrict__ boxes, float* __restrict__ areas, float* __restrict__ scores) {
  int n = blockIdx.x * blockDim.x + threadIdx.x;
  if (n >= NBOX) return;
  int p = n / 9, a = n % 9;
  int hh = p / 25, ww = p % 25;
  float Wlim = (float)(*Wp), Hlim = (float)(*Hp);
  float stride = (float)((*Wp) / 25);
  int ri = a / 3, si = a % 3;
  float ratio = (ri == 0) ? 0.5f : ((ri == 1) ? 1.0f : 2.0f);
  float size  = (si == 0) ? 128.f : ((si == 1) ? 256.f : 512.f);
  float hr = sqrtf(ratio);
  float wr = 1.0f / hr;
  float wsz = wr * size, hsz = hr * size;
  float bx1 = rintf(-wsz * 0.5f), by1 = rintf(-hsz * 0.5f);
  float bx2 = rintf( wsz * 0.5f), by2 = rintf( hsz * 0.5f);
  float sx = (float)ww * stride, sy = (float)hh * stride;
  float a0 = sx + bx1, a1 = sy + by1, a2 = sx + bx2, a3 = sy + by2;
  float ax = (a0 + a2) * 0.5f, ay = (a1 + a3) * 0.5f;
  float aw = fmaxf(a2 - a0, 1e-6f), ah = fmaxf(a3 - a1, 1e-6f);
  const float* row = clsreg + p * 54;
  float c0 = row[a * 2], c1 = row[a * 2 + 1];
  float m = fmaxf(c0, c1);
  float e0 = expf(c0 - m), e1 = expf(c1 - m);
  float prob = e1 / (e0 + e1);
  float tx = row[18 + a * 4 + 0], ty = row[18 + a * 4 + 1];
  float tw = row[18 + a * 4 + 2], th = row[18 + a * 4 + 3];
  float px = tx * aw + ax, py = ty * ah + ay;
  float pw = aw * fminf(expf(tw), 1e6f);
  float ph = ah * fminf(expf(th), 1e6f);
  float x1 = px - 0.5f * pw, y1 = py - 0.5f * ph;
  float x2 = px + 0.5f * pw, y2 = py + 0.5f * ph;
  x1 = fminf(fmaxf(x1, 0.f), Wlim - 1.f); x2 = fminf(fmaxf(x2, 0.f), Wlim - 1.f);
  y1 = fminf(fmaxf(y1, 0.f), Hlim - 1.f); y2 = fminf(fmaxf(y2, 0.f), Hlim - 1.f);
  float bw = fmaxf(x2 - x1, 0.f), bh = fmaxf(y2 - y1, 0.f);
  bool ok = (bw >= 1.0f) && (bh >= 1.0f);
  boxes[n * 4 + 0] = x1; boxes[n * 4 + 1] = y1;
  boxes[n * 4 + 2] = x2; boxes[n * 4 + 3] = y2;
  areas[n] = (x2 - x1) * (y2 - y1);
  scores[n] = ok ? prob : NEGINF;
}

// ---------------- greedy NMS, single block ----------------
__global__ __launch_bounds__(1024) void nms_kernel(
    const float* __restrict__ boxes, const float* __restrict__ areas,
    const float* __restrict__ scores_g, float* __restrict__ dout) {
  float* props  = dout;
  float* validf = dout + 4000;
  const int t = threadIdx.x;
  float bx1[6], by1[6], bx2[6], by2[6], bar[6], bs[6];
  int bn[6];
#pragma unroll
  for (int k = 0; k < 6; k++) {
    int n = t + k * 1024;
    bn[k] = n;
    if (n < NBOX) {
      bx1[k] = boxes[n * 4 + 0]; by1[k] = boxes[n * 4 + 1];
      bx2[k] = boxes[n * 4 + 2]; by2[k] = boxes[n * 4 + 3];
      bar[k] = areas[n]; bs[k] = scores_g[n];
    } else {
      bx1[k] = by1[k] = bx2[k] = by2[k] = 0.f; bar[k] = 0.f; bs[k] = NEGINF;
    }
  }
  __shared__ float rs[16];
  __shared__ int rn[16];
  __shared__ float bb[5];
  __shared__ int sel;
  const int lane = t & 63, wid = t >> 6;
  for (int i = 0; i < 1000; i++) {
    float ms = NEGINF; int mn = 0x7fffffff;
#pragma unroll
    for (int k = 0; k < 6; k++)
      if (bs[k] > ms || (bs[k] == ms && bn[k] < mn)) { ms = bs[k]; mn = bn[k]; }
#pragma unroll
    for (int off = 32; off >= 1; off >>= 1) {
      float os = __shfl_xor(ms, off);
      int   on = __shfl_xor(mn, off);
      if (os > ms || (os == ms && on < mn)) { ms = os; mn = on; }
    }
    if (lane == 0) { rs[wid] = ms; rn[wid] = mn; }
    __syncthreads();
    if (t == 0) {
      float S = NEGINF; int J = 0x7fffffff;
      for (int wdx = 0; wdx < 16; wdx++)
        if (rs[wdx] > S || (rs[wdx] == S && rn[wdx] < J)) { S = rs[wdx]; J = rn[wdx]; }
      sel = (S > NEGINF) ? J : -1;
    }
    __syncthreads();
    int j = sel;
    if (j < 0) {
      for (int z = i * 4 + t; z < 4000; z += 1024) props[z] = 0.f;
      for (int z = i + t; z < 1000; z += 1024) validf[z] = 0.f;
      return;
    }
    if (t == (j & 1023)) {
      int k = j >> 10;
      bb[0] = bx1[k]; bb[1] = by1[k]; bb[2] = bx2[k]; bb[3] = by2[k]; bb[4] = bar[k];
      bs[k] = NEGINF;
    }
    __syncthreads();
    float jx1 = bb[0], jy1 = bb[1], jx2 = bb[2], jy2 = bb[3], jar = bb[4];
#pragma unroll
    for (int k = 0; k < 6; k++) {
      float iw = fmaxf(fminf(bx2[k], jx2) - fmaxf(bx1[k], jx1), 0.f);
      float ih = fmaxf(fminf(by2[k], jy2) - fmaxf(by1[k], jy1), 0.f);
      float inter = iw * ih;
      float iou = inter / fmaxf(bar[k] + jar - inter, 1e-12f);
      if (iou > 0.7f) bs[k] = NEGINF;
    }
    if (t == 0) {
      props[i * 4 + 0] = jx1; props[i * 4 + 1] = jy1;
      props[i * 4 + 2] = jx2; props[i * 4 + 3] = jy2;
      validf[i] = 1.0f;
    }
  }
}

// ---------------- ROI max-pool -> bf16 feats [1024][25088], pad rows zeroed ----------------
__global__ __launch_bounds__(256) void roipool_kernel(
    const float* __restrict__ feat, const float* __restrict__ dout,
    const int* __restrict__ Wp, unsigned short* __restrict__ feats) {
  const int r = blockIdx.x;
  const int t = threadIdx.x;
  const float* props  = dout;
  const float* validf = dout + 4000;
  unsigned short* outr = feats + (size_t)r * 25088;
  bool dead = (r >= 1000) || (validf[r] == 0.0f);
  if (dead) {
    for (int i = t; i < 25088; i += 256) outr[i] = 0;
    return;
  }
  const float scale = 1.0f / (float)((*Wp) / 25);
  __shared__ int hs_[7], he_[7], ws_[7], we_[7];
  if (t < 7) {
    float fx1 = props[r * 4 + 0], fy1 = props[r * 4 + 1];
    float fx2 = props[r * 4 + 2], fy2 = props[r * 4 + 3];
    int x1 = (int)rintf(fx1 * scale), y1 = (int)rintf(fy1 * scale);
    int x2 = (int)rintf(fx2 * scale), y2 = (int)rintf(fy2 * scale);
    float roiw = (float)max(x2 - x1 + 1, 1);
    float roih = (float)max(y2 - y1 + 1, 1);
    float bw = roiw / 7.0f, bh = roih / 7.0f;
    float jf = (float)t;
    int w0 = (int)floorf(jf * bw) + x1;
    int w1 = (int)ceilf((jf + 1.f) * bw) + x1;
    int h0 = (int)floorf(jf * bh) + y1;
    int h1 = (int)ceilf((jf + 1.f) * bh) + y1;
    ws_[t] = min(max(w0, 0), 25); we_[t] = min(max(w1, 0), 25);
    hs_[t] = min(max(h0, 0), 25); he_[t] = min(max(h1, 0), 25);
  }
  __syncthreads();
  for (int idx = t; idx < 25088; idx += 256) {
    int c = idx / 49;
    int ij = idx % 49;
    int i = ij / 7, j = ij % 7;
    int h0 = hs_[i], h1 = min(he_[i], h0 + 6);
    int w0 = ws_[j], w1 = min(we_[j], w0 + 6);
    float m = NEGINF;
    const float* fp = feat + (size_t)c * 625;
    for (int y = h0; y < h1; y++)
      for (int x = w0; x < w1; x++)
        m = fmaxf(m, fp[y * 25 + x]);
    outr[idx] = (h0 < h1 && w0 < w1) ? f2bf(m) : 0;
  }
}

// ---------------- bf16 MFMA GEMM: C[128m x 128n] (f32) = A[M,K]bf16 * B[N,K]^T bf16 ----------
// m97 structure: BK=32, 4 waves, 4x4 16x16x32 tiles/wave, global_load_lds width 16.
__global__ __launch_bounds__(256) void gemm_bt_bf16(
    const unsigned short* __restrict__ A, int lda,
    const unsigned short* __restrict__ B, int ldb,
    const float* __restrict__ bias, float* __restrict__ C, int ldc,
    int K, int beta) {
  __shared__ unsigned short As[128 * 32];
  __shared__ unsigned short Bs[128 * 32];
  const int t = threadIdx.x;
  const int lane = t & 63;
  const int wv = t >> 6;
  const int wr = wv >> 1, wc = wv & 1;
  const int quad = lane >> 4, l16 = lane & 15;
  const int m0 = blockIdx.x * 128, n0 = blockIdx.y * 128;
  floatx4 acc[4][4];
#pragma unroll
  for (int mi = 0; mi < 4; mi++)
#pragma unroll
    for (int ni = 0; ni < 4; ni++) acc[mi][ni] = (floatx4){0.f, 0.f, 0.f, 0.f};
  const int srow = t >> 2;
  const int scol = (t & 3) * 8;
  const unsigned short* Ag0 = A + (size_t)(m0 + srow) * lda + scol;
  const unsigned short* Ag1 = A + (size_t)(m0 + 64 + srow) * lda + scol;
  const unsigned short* Bg0 = B + (size_t)(n0 + srow) * ldb + scol;
  const unsigned short* Bg1 = B + (size_t)(n0 + 64 + srow) * ldb + scol;
  unsigned short* la0 = As + t * 8;
  unsigned short* la1 = As + 2048 + t * 8;
  unsigned short* lb0 = Bs + t * 8;
  unsigned short* lb1 = Bs + 2048 + t * 8;
  for (int kt = 0; kt < K; kt += 32) {
    __syncthreads();
    gload16(Ag0 + kt, la0);
    gload16(Ag1 + kt, la1);
    gload16(Bg0 + kt, lb0);
    gload16(Bg1 + kt, lb1);
    __syncthreads();
    short8 af[4], bfr[4];
#pragma unroll
    for (int mi = 0; mi < 4; mi++)
      af[mi] = *(const short8*)(As + (wr * 64 + mi * 16 + l16) * 32 + quad * 8);
#pragma unroll
    for (int ni = 0; ni < 4; ni++)
      bfr[ni] = *(const short8*)(Bs + (wc * 64 + ni * 16 + l16) * 32 + quad * 8);
#pragma unroll
    for (int mi = 0; mi < 4; mi++)
#pragma unroll
      for (int ni = 0; ni < 4; ni++)
        acc[mi][ni] = __builtin_amdgcn_mfma_f32_16x16x32_bf16(af[mi], bfr[ni], acc[mi][ni], 0, 0, 0);
  }
#pragma unroll
  for (int mi = 0; mi < 4; mi++) {
#pragma unroll
    for (int ni = 0; ni < 4; ni++) {
      int gn = n0 + wc * 64 + ni * 16 + l16;
      float bv = bias ? bias[gn] : 0.f;
#pragma unroll
      for (int r = 0; r < 4; r++) {
        int gm = m0 + wr * 64 + mi * 16 + quad * 4 + r;
        size_t o = (size_t)gm * ldc + gn;
        float v = acc[mi][ni][r] + bv;
        C[o] = beta ? (C[o] + v) : v;
      }
    }
  }
}

// ---------------- weight / activation conversion kernels ----------------
// fc1 K-chunk: o[n][k] = bf16(w[n][koff+k]), n<4096, k<6272
__global__ __launch_bounds__(256) void cvt_fc1_chunk(
    const float* __restrict__ w, unsigned short* __restrict__ o, int koff) {
  int idx = blockIdx.x * 256 + threadIdx.x;
  int e = idx * 4;
  if (e >= 4096 * 6272) return;
  int n = e / 6272, k = e - n * 6272;
  float4 v = *(const float4*)(w + (size_t)n * 25088 + koff + k);
  ushort4 r = make_ushort4(f2bf(v.x), f2bf(v.y), f2bf(v.z), f2bf(v.w));
  *(ushort4*)(o + e) = r;
}

__global__ __launch_bounds__(256) void cvt_f32_bf16(
    const float* __restrict__ in, unsigned short* __restrict__ out, int n4) {
  int idx = blockIdx.x * 256 + threadIdx.x;
  if (idx >= n4) return;
  float4 v = *(const float4*)(in + (size_t)idx * 4);
  ushort4 r = make_ushort4(f2bf(v.x), f2bf(v.y), f2bf(v.z), f2bf(v.w));
  *(ushort4*)(out + (size_t)idx * 4) = r;
}

// h1bf = bf16(h1f + fc1_b[col]), 1024x4096
__global__ __launch_bounds__(256) void cvt_h1(
    const float* __restrict__ h1, const float* __restrict__ b,
    unsigned short* __restrict__ o) {
  int idx = blockIdx.x * 256 + threadIdx.x;
  int e = idx * 4;
  if (e >= 1024 * 4096) return;
  int col = e & 4095;
  float4 v = *(const float4*)(h1 + e);
  float4 bb = *(const float4*)(b + col);
  ushort4 r = make_ushort4(f2bf(v.x + bb.x), f2bf(v.y + bb.y),
                           f2bf(v.z + bb.z), f2bf(v.w + bb.w));
  *(ushort4*)(o + e) = r;
}

// ---------------- final fc: logits (21) + deltas (4), f32 ----------------
__global__ __launch_bounds__(256) void final_fc(
    const float* __restrict__ h2, const float* __restrict__ cw,
    const float* __restrict__ cb, const float* __restrict__ bw,
    const float* __restrict__ bb, float* __restrict__ logits,
    float* __restrict__ deltas) {
  int r = blockIdx.x;
  const float* x = h2 + (size_t)r * 4096;
  int lane = threadIdx.x & 63, w = threadIdx.x >> 6;
  for (int o = w; o < 25; o += 4) {
    const float* wt = (o < 21) ? (cw + (size_t)o * 4096) : (bw + (size_t)(o - 21) * 4096);
    float s = 0.f;
    for (int k = lane; k < 4096; k += 64) s = fmaf(x[k], wt[k], s);
#pragma unroll
    for (int off = 32; off >= 1; off >>= 1) s += __shfl_xor(s, off);
    if (lane == 0) {
      if (o < 21) logits[r * 21 + o] = s + cb[o];
      else        deltas[r * 4 + (o - 21)] = s + bb[o - 21];
    }
  }
}

extern "C" void kernel_launch(void* const* d_in, const int* in_sizes, int n_in,
                              void* d_out, int out_size, void* d_ws, size_t ws_size,
                              hipStream_t stream) {
  const float* features    = (const float*)d_in[0];
  const float* conv_w      = (const float*)d_in[1];
  const float* conv_b      = (const float*)d_in[2];
  const float* cls_w       = (const float*)d_in[3];
  const float* cls_b       = (const float*)d_in[4];
  const float* reg_w       = (const float*)d_in[5];
  const float* reg_b       = (const float*)d_in[6];
  const float* fc1_w       = (const float*)d_in[7];
  const float* fc1_b       = (const float*)d_in[8];
  const float* fc2_w       = (const float*)d_in[9];
  const float* fc2_b       = (const float*)d_in[10];
  const float* cls_score_w = (const float*)d_in[11];
  const float* cls_score_b = (const float*)d_in[12];
  const float* bbox_w      = (const float*)d_in[13];
  const float* bbox_b      = (const float*)d_in[14];
  const int*   Hp          = (const int*)d_in[15];
  const int*   Wp          = (const int*)d_in[16];
  float* out = (float*)d_out;

  // ---- workspace layout (bytes), peak = 121.1 MB ----
  char* w8 = (char*)d_ws;
  float* xt     = (float*)w8;                    // 1,280,000
  float* clsreg = xt + 320000;                   //   135,000
  float* boxes  = clsreg + 33750;                //    90,000
  float* areas  = boxes + 22500;                 //    22,500
  float* scores = areas + 5625;                  //    22,500  -> small end @1,550,000
  unsigned short* feats = (unsigned short*)(w8 + 1550000);    // 1024*25088*2 = 51,380,224
  float* h1f            = (float*)(w8 + 52930224);            // 1024*4096*4  = 16,777,216
  unsigned short* wchunk = (unsigned short*)(w8 + 69707440);  // 4096*6272*2  = 51,380,224 -> end 121,087,664
  // overlays (regions dead by the time they're used):
  unsigned short* fc2wb = wchunk;                              // 33,554,432 (after fc1 done)
  unsigned short* h1b   = (unsigned short*)(w8 + 69707440 + 33554432); // 8,388,608
  float* h2             = (float*)feats;                       // 16,777,216 (feats dead after fc1)

  conv3x3_relu<<<dim3(64, 5), 128, 0, stream>>>(features, conv_w, conv_b, xt);
  conv1x1_kernel<<<dim3(157), 256, 0, stream>>>(xt, cls_w, cls_b, reg_w, reg_b, clsreg);
  decode_kernel<<<dim3(23), 256, 0, stream>>>(clsreg, Hp, Wp, boxes, areas, scores);
  nms_kernel<<<dim3(1), 1024, 0, stream>>>(boxes, areas, scores, out);
  roipool_kernel<<<dim3(1024), 256, 0, stream>>>(features, out, Wp, feats);

  // fc1: (1024,25088)bf16 x (4096,25088)^T in 4 K-chunks of 6272, accumulate f32
  for (int kc = 0; kc < 4; kc++) {
    cvt_fc1_chunk<<<dim3(25088), 256, 0, stream>>>(fc1_w, wchunk, kc * 6272);
    gemm_bt_bf16<<<dim3(8, 32), 256, 0, stream>>>(
        feats + kc * 6272, 25088, wchunk, 6272, nullptr, h1f, 4096, 6272, kc > 0 ? 1 : 0);
  }
  cvt_h1<<<dim3(4096), 256, 0, stream>>>(h1f, fc1_b, h1b);

  // fc2: (1024,4096) x (4096,4096)^T + bias -> h2 f32
  cvt_f32_bf16<<<dim3(16384), 256, 0, stream>>>(fc2_w, fc2wb, 4194304);
  gemm_bt_bf16<<<dim3(8, 32), 256, 0, stream>>>(
      h1b, 4096, fc2wb, 4096, fc2_b, h2, 4096, 4096, 0);

  // logits + deltas
  final_fc<<<dim3(1000), 256, 0, stream>>>(h2, cls_score_w, cls_score_b,
                                           bbox_w, bbox_b, out + 5000, out + 26000);
}